// Round 7
// baseline (376.783 us; speedup 1.0000x reference)
//
#include <hip/hip_runtime.h>

#define NSL 8
#define DIN 384
#define DS 128
#define BATCH 32
#define NPOS 4096
#define LN_EPS 1e-5f
#define THRESH 0.9f
#define NCH 128         // feature chunks per batch (32 rows each)

// attn = 0.125 exactly (softmax of identical logits across slots);
// sum over N = 512.0 exactly; 512.0f + 1e-8f == 512.0f; 0.125/512 = 2^-12
#define ATTN_NORM_C 0.000244140625f

// ---------------- P0: transpose Wv / W1 / W2 so output-threads stream rows ----------------
__global__ __launch_bounds__(256) void prep_kernel(const float* __restrict__ Wv,
                                                   const float* __restrict__ W1,
                                                   const float* __restrict__ W2,
                                                   float* __restrict__ WvT,    // [128][384]
                                                   float* __restrict__ W1T,    // [256][128]
                                                   float* __restrict__ W2T) {  // [128][256]
    int idx = blockIdx.x * 256 + threadIdx.x;
    if (idx < 49152) {            // WvT[j][k] = Wv[k][j]
        int j = idx / 384, k = idx % 384;
        WvT[idx] = Wv[k * 128 + j];
    }
    if (idx < 32768) {            // W1T[j][k] = W1[k][j]
        int j = idx / 128, k = idx % 128;
        W1T[idx] = W1[k * 256 + j];
    }
    if (idx < 32768) {            // W2T[j][k] = W2[k][j]
        int j = idx / 256, k = idx % 256;
        W2T[idx] = W2[k * 128 + j];
    }
}

// ---------------- K1: streaming  Σ_rows rstd·(x−μ)  (per column) + attn fill ----------------
// 128-thread blocks, 32 rows/block -> 4096 blocks = 32 waves/CU (was 16).
// 16-lane row groups, float4 loads, register double-buffer (prefetch next 4-row set).
__global__ __launch_bounds__(128) void colsum_kernel(const float* __restrict__ feat,
                                                     float* __restrict__ G_part,   // [32][NCH][384]
                                                     float* __restrict__ out_attn) {
    __shared__ float S_lds[8][384];   // 12 KB
    int t = threadIdx.x, w = t >> 6, lane = t & 63;
    int group = lane >> 4, gl = lane & 15;
    int gg = w * 4 + group;           // 8 row-groups per block
    int b = blockIdx.y, ch = blockIdx.x;
    int row0 = ch * 32 + gg;
    const float4* fbase = (const float4*)(feat + ((size_t)b * NPOS + row0) * DIN);

    float4 acc[6];
#pragma unroll
    for (int s = 0; s < 6; s++) { acc[s].x = 0.f; acc[s].y = 0.f; acc[s].z = 0.f; acc[s].w = 0.f; }

    float4 xA[6], xB[6];
#pragma unroll
    for (int s = 0; s < 6; s++) xA[s] = fbase[s * 16 + gl];

#pragma unroll
    for (int j = 0; j < 4; j++) {     // each group: rows gg + 8*j
        if (j < 3) {
            const float4* rp = fbase + (size_t)(j + 1) * 768;   // +8 rows = 8*96 float4
#pragma unroll
            for (int s = 0; s < 6; s++) xB[s] = rp[s * 16 + gl];
        }
        float sm = 0.f, sq = 0.f;
#pragma unroll
        for (int s = 0; s < 6; s++) {
            sm += xA[s].x + xA[s].y + xA[s].z + xA[s].w;
            sq += xA[s].x * xA[s].x + xA[s].y * xA[s].y + xA[s].z * xA[s].z + xA[s].w * xA[s].w;
        }
#pragma unroll
        for (int m = 1; m < 16; m <<= 1) {
            sm += __shfl_xor(sm, m, 64);
            sq += __shfl_xor(sq, m, 64);
        }
        float mean = sm * (1.f / 384.f);
        float var = sq * (1.f / 384.f) - mean * mean;
        float rstd = rsqrtf(var + LN_EPS);
#pragma unroll
        for (int s = 0; s < 6; s++) {
            acc[s].x += (xA[s].x - mean) * rstd;
            acc[s].y += (xA[s].y - mean) * rstd;
            acc[s].z += (xA[s].z - mean) * rstd;
            acc[s].w += (xA[s].w - mean) * rstd;
        }
#pragma unroll
        for (int s = 0; s < 6; s++) xA[s] = xB[s];
    }
#pragma unroll
    for (int s = 0; s < 6; s++)
        *(float4*)&S_lds[gg][s * 64 + gl * 4] = acc[s];
    __syncthreads();
    // fixed-order combine of the 8 partials -> block partial (deterministic)
#pragma unroll
    for (int i = 0; i < 3; i++) {
        int q = t + i * 128;
        float v = 0.f;
#pragma unroll
        for (int r = 0; r < 8; r++) v += S_lds[r][q];
        G_part[((size_t)b * NCH + ch) * 384 + q] = v;
    }
    // attn output is exactly 0.125 everywhere
    int s8 = t >> 4, p = (t & 15) * 2;
    float* ao = out_attn + ((size_t)(b * 8 + s8)) * NPOS + ch * 32 + p;
    *(float2*)ao = make_float2(0.125f, 0.125f);
}

// ---------------- batched contiguous-row dot: 32 float4 loads in flight per RT ----------------
template <int N4>
__device__ __forceinline__ float dot_row(const float4* __restrict__ wr, const float* x) {
    float acc = 0.f;
#pragma unroll
    for (int kb = 0; kb < N4; kb += 32) {
        float4 w[32];
#pragma unroll
        for (int i = 0; i < 32; i++) w[i] = wr[kb + i];
#pragma unroll
        for (int i = 0; i < 32; i++) {
            int k = (kb + i) * 4;
            acc += x[k] * w[i].x + x[k + 1] * w[i].y + x[k + 2] * w[i].z + x[k + 3] * w[i].w;
        }
    }
    return acc;
}

// ---------------- K2: batched-load matvecs; 3x (GRU + LN + MLP); merge outputs ----------------
__global__ __launch_bounds__(384) void slots_kernel(
    const float* __restrict__ G_part,
    const float* __restrict__ g_in, const float* __restrict__ b_in,
    const float* __restrict__ WvT,
    const float* __restrict__ slot_mu,
    const float* __restrict__ W_ih, const float* __restrict__ W_hh,
    const float* __restrict__ b_ih, const float* __restrict__ b_hh,
    const float* __restrict__ gm, const float* __restrict__ bm,
    const float* __restrict__ W1T, const float* __restrict__ b1v,
    const float* __restrict__ W2T, const float* __restrict__ b2v,
    float* __restrict__ out_merged, float* __restrict__ out_mm,
    float* __restrict__ out_raw)
{
    __shared__ float S_l[384], u_l[128], h_l[128], m_l[128], hid_l[256];
    __shared__ float gx_l[384], gh_l[384];
    __shared__ float red[4];
    int b = blockIdx.x, t = threadIdx.x;

    // colsum = g * Σ_ch partial + 4096 * b   (batched, fixed ascending order)
    {
        float s = 0.f;
#pragma unroll
        for (int ob = 0; ob < NCH; ob += 32) {
            float r[32];
#pragma unroll
            for (int i = 0; i < 32; i++)
                r[i] = G_part[((size_t)b * NCH + ob + i) * 384 + t];
#pragma unroll
            for (int i = 0; i < 32; i++) s += r[i];
        }
        S_l[t] = g_in[t] * s + 4096.f * b_in[t];
    }
    __syncthreads();

    // u = attn_norm * (colsum @ Wv)
    if (t < 128) {
        float u = dot_row<96>((const float4*)(WvT + t * 384), S_l);
        u_l[t] = u * ATTN_NORM_C;
        h_l[t] = slot_mu[t];
    }
    __syncthreads();

    // gx = W_ih @ u + b_ih  (iteration-invariant; W_ih row t contiguous)
    gx_l[t] = b_ih[t] + dot_row<32>((const float4*)(W_ih + t * 128), u_l);
    __syncthreads();

    float h = (t < 128) ? h_l[t] : 0.f;
    float hn = 0.f;
    for (int it = 0; it < 3; it++) {
        gh_l[t] = b_hh[t] + dot_row<32>((const float4*)(W_hh + t * 128), h_l);
        __syncthreads();
        if (t < 128) {
            float r = 1.f / (1.f + expf(-(gx_l[t] + gh_l[t])));
            float z = 1.f / (1.f + expf(-(gx_l[128 + t] + gh_l[128 + t])));
            float nn = tanhf(gx_l[256 + t] + r * gh_l[256 + t]);
            hn = (1.f - z) * nn + z * h;
            float s = hn, sq = hn * hn;
#pragma unroll
            for (int m = 1; m < 64; m <<= 1) { s += __shfl_xor(s, m, 64); sq += __shfl_xor(sq, m, 64); }
            if ((t & 63) == 0) { red[(t >> 6) * 2] = s; red[(t >> 6) * 2 + 1] = sq; }
        }
        __syncthreads();
        if (t < 128) {
            float s = red[0] + red[2], sq = red[1] + red[3];
            float mean = s * (1.f / 128.f), var = sq * (1.f / 128.f) - mean * mean;
            float rstd = rsqrtf(var + LN_EPS);
            m_l[t] = (hn - mean) * rstd * gm[t] + bm[t];
        }
        __syncthreads();
        if (t < 256) {
            float a = b1v[t] + dot_row<32>((const float4*)(W1T + t * 128), m_l);
            hid_l[t] = a / (1.f + expf(-a));   // silu
        }
        __syncthreads();
        if (t < 128) {
            float o = hn + b2v[t] + dot_row<64>((const float4*)(W2T + t * 256), hid_l);
            h = o;
            h_l[t] = o;
        }
        __syncthreads();
    }

    // merge: all 8 slots identical; off-diag sim = cos(h,h)
    if (t < 128) {
        float s2 = h * h;
#pragma unroll
        for (int m = 1; m < 64; m <<= 1) s2 += __shfl_xor(s2, m, 64);
        if ((t & 63) == 0) red[t >> 6] = s2;
    }
    __syncthreads();
    if (t < 128) {
        float ss = red[0] + red[1];
        float nrm = fmaxf(sqrtf(ss), 1e-12f);
        float simv = ss / (nrm * nrm);
        int allmerge = (simv > THRESH) ? 1 : 0;
#pragma unroll
        for (int sl = 0; sl < 8; sl++) {
            out_raw[((size_t)(b * 8 + sl)) * 128 + t] = h;
            float mv = (sl == 0) ? h : (allmerge ? 0.f : h);
            out_merged[((size_t)(b * 8 + sl)) * 128 + t] = mv;
        }
        if (t < 8) out_mm[b * 8 + t] = allmerge ? 0.f : (float)t;
    }
}

extern "C" void kernel_launch(void* const* d_in, const int* in_sizes, int n_in,
                              void* d_out, int out_size, void* d_ws, size_t ws_size,
                              hipStream_t stream) {
    const float* feat    = (const float*)d_in[0];
    const float* ln_in_g = (const float*)d_in[1];
    const float* ln_in_b = (const float*)d_in[2];
    const float* Wv      = (const float*)d_in[4];
    const float* W_ih    = (const float*)d_in[8];
    const float* W_hh    = (const float*)d_in[9];
    const float* b_ih    = (const float*)d_in[10];
    const float* b_hh    = (const float*)d_in[11];
    const float* ln_m_g  = (const float*)d_in[12];
    const float* ln_m_b  = (const float*)d_in[13];
    const float* W1      = (const float*)d_in[14];
    const float* b1      = (const float*)d_in[15];
    const float* W2      = (const float*)d_in[16];
    const float* b2      = (const float*)d_in[17];
    const float* slot_mu = (const float*)d_in[18];

    float* out        = (float*)d_out;
    float* out_merged = out;                       // 32768
    float* out_attn   = out + 32768;               // 1048576
    float* out_mm     = out + 32768 + 1048576;     // 256
    float* out_raw    = out_mm + 256;              // 32768

    float* G_part = (float*)d_ws;                  // [32][128][384] = 6,291,456 B
    float* WvT    = G_part + 32 * NCH * 384;       // [128][384] = 196,608 B
    float* W1T    = WvT + 49152;                   // [256][128] = 131,072 B
    float* W2T    = W1T + 32768;                   // [128][256] = 131,072 B

    prep_kernel<<<192, 256, 0, stream>>>(Wv, W1, W2, WvT, W1T, W2T);
    colsum_kernel<<<dim3(NCH, BATCH), 128, 0, stream>>>(feat, G_part, out_attn);
    slots_kernel<<<32, 384, 0, stream>>>(G_part, ln_in_g, ln_in_b, WvT, slot_mu,
                                         W_ih, W_hh, b_ih, b_hh, ln_m_g, ln_m_b,
                                         W1T, b1, W2T, b2,
                                         out_merged, out_mm, out_raw);
}

// Round 8
// 352.341 us; speedup vs baseline: 1.0694x; 1.0694x over previous
//
#include <hip/hip_runtime.h>

#define NSL 8
#define DIN 384
#define DS 128
#define BATCH 32
#define NPOS 4096
#define LN_EPS 1e-5f
#define THRESH 0.9f
#define NCH 32          // feature chunks per batch (128 rows each)

// attn = 0.125 exactly (softmax of identical logits across slots);
// sum over N = 512.0 exactly; 512.0f + 1e-8f == 512.0f; 0.125/512 = 2^-12
#define ATTN_NORM_C 0.000244140625f

// ---------------- P0: transpose W_ih / W_hh -> [128][384] (k-major, coalesced in j) ----------------
__global__ __launch_bounds__(256) void prep_kernel(const float* __restrict__ Wih,
                                                   const float* __restrict__ Whh,
                                                   float* __restrict__ WihT,
                                                   float* __restrict__ WhhT) {
    int idx = blockIdx.x * 256 + threadIdx.x;   // 384*128 = 49152
    if (idx < 49152) {
        int j = idx / 128, k = idx % 128;       // Wih[j][k]
        WihT[k * 384 + j] = Wih[idx];
        WhhT[k * 384 + j] = Whh[idx];
    }
}

// ---------------- K1: streaming  Σ_rows rstd·(x−μ)  (per column) + attn fill ----------------
// EXACT best-known version (round-5 proposal): NCH=32, 256 threads, 16-lane row
// groups, float4 loads, register double-buffer (prefetch next 4-row set).
__global__ __launch_bounds__(256) void colsum_kernel(const float* __restrict__ feat,
                                                     float* __restrict__ G_part,   // [32][NCH][384]
                                                     float* __restrict__ out_attn) {
    __shared__ float S_lds[16][384];   // 24 KB
    int t = threadIdx.x, w = t >> 6, lane = t & 63;
    int group = lane >> 4, gl = lane & 15;
    int b = blockIdx.y, ch = blockIdx.x;
    int row0 = ch * 128 + w * 32 + group;
    const float4* fbase = (const float4*)(feat + ((size_t)b * NPOS + row0) * DIN);

    float4 acc[6];
#pragma unroll
    for (int s = 0; s < 6; s++) { acc[s].x = 0.f; acc[s].y = 0.f; acc[s].z = 0.f; acc[s].w = 0.f; }

    float4 xA[6], xB[6];
#pragma unroll
    for (int s = 0; s < 6; s++) xA[s] = fbase[s * 16 + gl];

#pragma unroll
    for (int j = 0; j < 8; j++) {
        if (j < 7) {
            const float4* rp = fbase + (size_t)(j + 1) * 384;
#pragma unroll
            for (int s = 0; s < 6; s++) xB[s] = rp[s * 16 + gl];
        }
        float sm = 0.f, sq = 0.f;
#pragma unroll
        for (int s = 0; s < 6; s++) {
            sm += xA[s].x + xA[s].y + xA[s].z + xA[s].w;
            sq += xA[s].x * xA[s].x + xA[s].y * xA[s].y + xA[s].z * xA[s].z + xA[s].w * xA[s].w;
        }
#pragma unroll
        for (int m = 1; m < 16; m <<= 1) {
            sm += __shfl_xor(sm, m, 64);
            sq += __shfl_xor(sq, m, 64);
        }
        float mean = sm * (1.f / 384.f);
        float var = sq * (1.f / 384.f) - mean * mean;
        float rstd = rsqrtf(var + LN_EPS);
#pragma unroll
        for (int s = 0; s < 6; s++) {
            acc[s].x += (xA[s].x - mean) * rstd;
            acc[s].y += (xA[s].y - mean) * rstd;
            acc[s].z += (xA[s].z - mean) * rstd;
            acc[s].w += (xA[s].w - mean) * rstd;
        }
#pragma unroll
        for (int s = 0; s < 6; s++) xA[s] = xB[s];
    }
    int gr = w * 4 + group;
#pragma unroll
    for (int s = 0; s < 6; s++)
        *(float4*)&S_lds[gr][s * 64 + gl * 4] = acc[s];
    __syncthreads();
    for (int q = t; q < 384; q += 256) {
        float v = 0.f;
#pragma unroll
        for (int r = 0; r < 16; r++) v += S_lds[r][q];
        G_part[((size_t)b * NCH + ch) * 384 + q] = v;
    }
    int s8 = t >> 5, p = t & 31;
    size_t ao = ((size_t)(b * 8 + s8)) * NPOS + ch * 128;
    out_attn[ao + p] = 0.125f;
    out_attn[ao + 32 + p] = 0.125f;
    out_attn[ao + 64 + p] = 0.125f;
    out_attn[ao + 96 + p] = 0.125f;
}

// ---------------- K2: compact-code matvecs (rolled outer, 16 scalar loads in flight) ----------------
// All weight reads are wave-coalesced in the THREAD index (k-major layouts);
// outer loops NOT unrolled -> small body, warm I-cache.
__global__ __launch_bounds__(384) void slots_kernel(
    const float* __restrict__ G_part,
    const float* __restrict__ g_in, const float* __restrict__ b_in,
    const float* __restrict__ Wv,      // [384][128] original
    const float* __restrict__ slot_mu,
    const float* __restrict__ WihT,    // [128][384]
    const float* __restrict__ WhhT,    // [128][384]
    const float* __restrict__ b_ih, const float* __restrict__ b_hh,
    const float* __restrict__ gm, const float* __restrict__ bm,
    const float* __restrict__ W1,      // [128][256] original
    const float* __restrict__ b1v,
    const float* __restrict__ W2,      // [256][128] original
    const float* __restrict__ b2v,
    float* __restrict__ out_merged, float* __restrict__ out_mm,
    float* __restrict__ out_raw)
{
    __shared__ float S_l[384], part3[3][128], u_l[128], h_l[128], m_l[128], hid_l[256];
    __shared__ float gx_l[384], gh_l[384];
    __shared__ float red[4];
    int b = blockIdx.x, t = threadIdx.x;
    int tw = t >> 7, tl = t & 127;

    // colsum = g * Σ_ch partial + 4096*b  (ascending ch, single accumulator)
    {
        float s = 0.f;
#pragma unroll 1
        for (int ob = 0; ob < NCH; ob += 8) {
            float r[8];
#pragma unroll
            for (int i = 0; i < 8; i++) r[i] = G_part[((size_t)b * NCH + ob + i) * 384 + t];
#pragma unroll
            for (int i = 0; i < 8; i++) s += r[i];
        }
        S_l[t] = g_in[t] * s + 4096.f * b_in[t];
    }
    __syncthreads();

    // u partials: 3-way k-split (thread (tw,tl) covers k in [tw*128, tw*128+128))
    {
        float up = 0.f;
#pragma unroll 1
        for (int kb = 0; kb < 128; kb += 16) {
            float w[16];
#pragma unroll
            for (int i = 0; i < 16; i++) w[i] = Wv[(size_t)(tw * 128 + kb + i) * 128 + tl];
#pragma unroll
            for (int i = 0; i < 16; i++) up += S_l[tw * 128 + kb + i] * w[i];
        }
        part3[tw][tl] = up;
    }
    __syncthreads();
    if (t < 128) {
        u_l[t] = (part3[0][t] + part3[1][t] + part3[2][t]) * ATTN_NORM_C;
        h_l[t] = slot_mu[t];
    }
    __syncthreads();

    // gx = W_ih @ u + b_ih (iteration-invariant)
    {
        float ax = b_ih[t];
#pragma unroll 1
        for (int kb = 0; kb < 128; kb += 16) {
            float w[16];
#pragma unroll
            for (int i = 0; i < 16; i++) w[i] = WihT[(size_t)(kb + i) * 384 + t];
#pragma unroll
            for (int i = 0; i < 16; i++) ax += u_l[kb + i] * w[i];
        }
        gx_l[t] = ax;
    }
    __syncthreads();

    float h = (t < 128) ? h_l[t] : 0.f;
    float hn = 0.f;
#pragma unroll 1
    for (int it = 0; it < 3; it++) {
        // gh = W_hh @ h + b_hh
        {
            float ah = b_hh[t];
#pragma unroll 1
            for (int kb = 0; kb < 128; kb += 16) {
                float w[16];
#pragma unroll
                for (int i = 0; i < 16; i++) w[i] = WhhT[(size_t)(kb + i) * 384 + t];
#pragma unroll
                for (int i = 0; i < 16; i++) ah += h_l[kb + i] * w[i];
            }
            gh_l[t] = ah;
        }
        __syncthreads();
        if (t < 128) {
            float r = 1.f / (1.f + expf(-(gx_l[t] + gh_l[t])));
            float z = 1.f / (1.f + expf(-(gx_l[128 + t] + gh_l[128 + t])));
            float nn = tanhf(gx_l[256 + t] + r * gh_l[256 + t]);
            hn = (1.f - z) * nn + z * h;
            float s = hn, sq = hn * hn;
#pragma unroll
            for (int m = 1; m < 64; m <<= 1) { s += __shfl_xor(s, m, 64); sq += __shfl_xor(sq, m, 64); }
            if ((t & 63) == 0) { red[(t >> 6) * 2] = s; red[(t >> 6) * 2 + 1] = sq; }
        }
        __syncthreads();
        if (t < 128) {
            float s = red[0] + red[2], sq = red[1] + red[3];
            float mean = s * (1.f / 128.f), var = sq * (1.f / 128.f) - mean * mean;
            float rstd = rsqrtf(var + LN_EPS);
            m_l[t] = (hn - mean) * rstd * gm[t] + bm[t];
        }
        __syncthreads();
        if (t < 256) {   // MLP layer 1
            float a = b1v[t];
#pragma unroll 1
            for (int kb = 0; kb < 128; kb += 16) {
                float w[16];
#pragma unroll
                for (int i = 0; i < 16; i++) w[i] = W1[(size_t)(kb + i) * 256 + t];
#pragma unroll
                for (int i = 0; i < 16; i++) a += m_l[kb + i] * w[i];
            }
            hid_l[t] = a / (1.f + expf(-a));   // silu
        }
        __syncthreads();
        if (t < 256) {   // MLP layer 2, 2-way k-split
            int w2 = t >> 7, l2 = t & 127;
            float o = 0.f;
#pragma unroll 1
            for (int kb = 0; kb < 128; kb += 16) {
                float w[16];
#pragma unroll
                for (int i = 0; i < 16; i++) w[i] = W2[(size_t)(w2 * 128 + kb + i) * 128 + l2];
#pragma unroll
                for (int i = 0; i < 16; i++) o += hid_l[w2 * 128 + kb + i] * w[i];
            }
            part3[w2][l2] = o;
        }
        __syncthreads();
        if (t < 128) {
            h = hn + b2v[t] + (part3[0][t] + part3[1][t]);
            h_l[t] = h;
        }
        __syncthreads();
    }

    // merge: all 8 slots identical; off-diag sim = cos(h,h)
    if (t < 128) {
        float s2 = h * h;
#pragma unroll
        for (int m = 1; m < 64; m <<= 1) s2 += __shfl_xor(s2, m, 64);
        if ((t & 63) == 0) red[t >> 6] = s2;
    }
    __syncthreads();
    if (t < 128) {
        float ss = red[0] + red[1];
        float nrm = fmaxf(sqrtf(ss), 1e-12f);
        float simv = ss / (nrm * nrm);
        int allmerge = (simv > THRESH) ? 1 : 0;
#pragma unroll
        for (int sl = 0; sl < 8; sl++) {
            out_raw[((size_t)(b * 8 + sl)) * 128 + t] = h;
            float mv = (sl == 0) ? h : (allmerge ? 0.f : h);
            out_merged[((size_t)(b * 8 + sl)) * 128 + t] = mv;
        }
        if (t < 8) out_mm[b * 8 + t] = allmerge ? 0.f : (float)t;
    }
}

extern "C" void kernel_launch(void* const* d_in, const int* in_sizes, int n_in,
                              void* d_out, int out_size, void* d_ws, size_t ws_size,
                              hipStream_t stream) {
    const float* feat    = (const float*)d_in[0];
    const float* ln_in_g = (const float*)d_in[1];
    const float* ln_in_b = (const float*)d_in[2];
    const float* Wv      = (const float*)d_in[4];
    const float* W_ih    = (const float*)d_in[8];
    const float* W_hh    = (const float*)d_in[9];
    const float* b_ih    = (const float*)d_in[10];
    const float* b_hh    = (const float*)d_in[11];
    const float* ln_m_g  = (const float*)d_in[12];
    const float* ln_m_b  = (const float*)d_in[13];
    const float* W1      = (const float*)d_in[14];
    const float* b1      = (const float*)d_in[15];
    const float* W2      = (const float*)d_in[16];
    const float* b2      = (const float*)d_in[17];
    const float* slot_mu = (const float*)d_in[18];

    float* out        = (float*)d_out;
    float* out_merged = out;                       // 32768
    float* out_attn   = out + 32768;               // 1048576
    float* out_mm     = out + 32768 + 1048576;     // 256
    float* out_raw    = out_mm + 256;              // 32768

    float* G_part = (float*)d_ws;                  // [32][32][384] = 1,572,864 B
    float* WihT   = G_part + 32 * NCH * 384;       // [128][384] = 196,608 B
    float* WhhT   = WihT + 49152;                  // [128][384] = 196,608 B

    prep_kernel<<<192, 256, 0, stream>>>(W_ih, W_hh, WihT, WhhT);
    colsum_kernel<<<dim3(NCH, BATCH), 256, 0, stream>>>(feat, G_part, out_attn);
    slots_kernel<<<32, 384, 0, stream>>>(G_part, ln_in_g, ln_in_b, Wv, slot_mu,
                                         WihT, WhhT, b_ih, b_hh, ln_m_g, ln_m_b,
                                         W1, b1, W2, b2,
                                         out_merged, out_mm, out_raw);
}

// Round 9
// 338.883 us; speedup vs baseline: 1.1118x; 1.0397x over previous
//
#include <hip/hip_runtime.h>

#define NSL 8
#define DIN 384
#define DS 128
#define BATCH 32
#define NPOS 4096
#define LN_EPS 1e-5f
#define THRESH 0.9f
#define NCH 32          // feature chunks per batch (128 rows each)

// attn = 0.125 exactly (softmax of identical logits across slots);
// sum over N = 512.0 exactly; 512.0f + 1e-8f == 512.0f; 0.125/512 = 2^-12
#define ATTN_NORM_C 0.000244140625f

// ---------------- P0: transpose W_ih / W_hh -> [128][384] (k-major, coalesced in j) ----------------
__global__ __launch_bounds__(256) void prep_kernel(const float* __restrict__ Wih,
                                                   const float* __restrict__ Whh,
                                                   float* __restrict__ WihT,
                                                   float* __restrict__ WhhT) {
    int idx = blockIdx.x * 256 + threadIdx.x;   // 384*128 = 49152
    if (idx < 49152) {
        int j = idx / 128, k = idx % 128;       // Wih[j][k]
        WihT[k * 384 + j] = Wih[idx];
        WhhT[k * 384 + j] = Whh[idx];
    }
}

// ---------------- K1: streaming  Σ_rows rstd·(x−μ)  (per column) + attn fill ----------------
// BYTE-IDENTICAL to round 8 (at its ~32 us HBM roofline).
__global__ __launch_bounds__(256) void colsum_kernel(const float* __restrict__ feat,
                                                     float* __restrict__ G_part,   // [32][NCH][384]
                                                     float* __restrict__ out_attn) {
    __shared__ float S_lds[16][384];   // 24 KB
    int t = threadIdx.x, w = t >> 6, lane = t & 63;
    int group = lane >> 4, gl = lane & 15;
    int b = blockIdx.y, ch = blockIdx.x;
    int row0 = ch * 128 + w * 32 + group;
    const float4* fbase = (const float4*)(feat + ((size_t)b * NPOS + row0) * DIN);

    float4 acc[6];
#pragma unroll
    for (int s = 0; s < 6; s++) { acc[s].x = 0.f; acc[s].y = 0.f; acc[s].z = 0.f; acc[s].w = 0.f; }

    float4 xA[6], xB[6];
#pragma unroll
    for (int s = 0; s < 6; s++) xA[s] = fbase[s * 16 + gl];

#pragma unroll
    for (int j = 0; j < 8; j++) {
        if (j < 7) {
            const float4* rp = fbase + (size_t)(j + 1) * 384;
#pragma unroll
            for (int s = 0; s < 6; s++) xB[s] = rp[s * 16 + gl];
        }
        float sm = 0.f, sq = 0.f;
#pragma unroll
        for (int s = 0; s < 6; s++) {
            sm += xA[s].x + xA[s].y + xA[s].z + xA[s].w;
            sq += xA[s].x * xA[s].x + xA[s].y * xA[s].y + xA[s].z * xA[s].z + xA[s].w * xA[s].w;
        }
#pragma unroll
        for (int m = 1; m < 16; m <<= 1) {
            sm += __shfl_xor(sm, m, 64);
            sq += __shfl_xor(sq, m, 64);
        }
        float mean = sm * (1.f / 384.f);
        float var = sq * (1.f / 384.f) - mean * mean;
        float rstd = rsqrtf(var + LN_EPS);
#pragma unroll
        for (int s = 0; s < 6; s++) {
            acc[s].x += (xA[s].x - mean) * rstd;
            acc[s].y += (xA[s].y - mean) * rstd;
            acc[s].z += (xA[s].z - mean) * rstd;
            acc[s].w += (xA[s].w - mean) * rstd;
        }
#pragma unroll
        for (int s = 0; s < 6; s++) xA[s] = xB[s];
    }
    int gr = w * 4 + group;
#pragma unroll
    for (int s = 0; s < 6; s++)
        *(float4*)&S_lds[gr][s * 64 + gl * 4] = acc[s];
    __syncthreads();
    for (int q = t; q < 384; q += 256) {
        float v = 0.f;
#pragma unroll
        for (int r = 0; r < 16; r++) v += S_lds[r][q];
        G_part[((size_t)b * NCH + ch) * 384 + q] = v;
    }
    int s8 = t >> 5, p = t & 31;
    size_t ao = ((size_t)(b * 8 + s8)) * NPOS + ch * 128;
    out_attn[ao + p] = 0.125f;
    out_attn[ao + 32 + p] = 0.125f;
    out_attn[ao + 64 + p] = 0.125f;
    out_attn[ao + 96 + p] = 0.125f;
}

// ---------------- K2: 1024-thread block, 2-D (output x k-chunk) split matvecs ----------------
// One block per batch; every matvec phase uses all 16 waves; fixed-order LDS
// combines keep results deterministic and identical across batches/slots.
__global__ __launch_bounds__(1024) void slots_kernel(
    const float* __restrict__ G_part,
    const float* __restrict__ g_in, const float* __restrict__ b_in,
    const float* __restrict__ Wv,      // [384][128]
    const float* __restrict__ slot_mu,
    const float* __restrict__ WihT,    // [128][384]
    const float* __restrict__ WhhT,    // [128][384]
    const float* __restrict__ b_ih, const float* __restrict__ b_hh,
    const float* __restrict__ gm, const float* __restrict__ bm,
    const float* __restrict__ W1,      // [128][256]
    const float* __restrict__ b1v,
    const float* __restrict__ W2,      // [256][128]
    const float* __restrict__ b2v,
    float* __restrict__ out_merged, float* __restrict__ out_mm,
    float* __restrict__ out_raw)
{
    __shared__ float S_l[384], u_l[128], h_l[128], m_l[128], hid_l[256];
    __shared__ float gx_l[384], gh_l[384];
    __shared__ float p2[2][384];
    __shared__ float p4[4][256];
    __shared__ float p8[8][128];
    __shared__ float red[4];
    int b = blockIdx.x, t = threadIdx.x;

    // --- A: colsum partials: 384 q x 2 chunk-halves ---
    if (t < 768) {
        int hc = t / 384, q = t % 384;
        float s = 0.f;
#pragma unroll 1
        for (int ob = 0; ob < 16; ob += 8) {
            float r[8];
#pragma unroll
            for (int i = 0; i < 8; i++)
                r[i] = G_part[((size_t)b * NCH + hc * 16 + ob + i) * 384 + q];
#pragma unroll
            for (int i = 0; i < 8; i++) s += r[i];
        }
        p2[hc][q] = s;
    }
    __syncthreads();
    if (t < 384) S_l[t] = g_in[t] * (p2[0][t] + p2[1][t]) + 4096.f * b_in[t];
    __syncthreads();

    // --- B: u partials: 128 d x 8 k-chunks (k=48 each) ---
    {
        int kc = t >> 7, d = t & 127;
        float s = 0.f;
#pragma unroll 1
        for (int kb = 0; kb < 48; kb += 16) {
            float w[16];
#pragma unroll
            for (int i = 0; i < 16; i++)
                w[i] = Wv[(size_t)(kc * 48 + kb + i) * 128 + d];
#pragma unroll
            for (int i = 0; i < 16; i++) s += S_l[kc * 48 + kb + i] * w[i];
        }
        p8[kc][d] = s;
    }
    __syncthreads();
    if (t < 128) {
        float s = 0.f;
#pragma unroll
        for (int kc = 0; kc < 8; kc++) s += p8[kc][t];
        u_l[t] = s * ATTN_NORM_C;
        h_l[t] = slot_mu[t];
    }
    __syncthreads();

    // --- C: gx partials: 384 j x 2 k-chunks (k=64 each); iteration-invariant ---
    if (t < 768) {
        int kc = t / 384, j = t % 384;
        float s = 0.f;
#pragma unroll 1
        for (int kb = 0; kb < 64; kb += 16) {
            float w[16];
#pragma unroll
            for (int i = 0; i < 16; i++)
                w[i] = WihT[(size_t)(kc * 64 + kb + i) * 384 + j];
#pragma unroll
            for (int i = 0; i < 16; i++) s += u_l[kc * 64 + kb + i] * w[i];
        }
        p2[kc][j] = s;
    }
    __syncthreads();
    if (t < 384) gx_l[t] = b_ih[t] + p2[0][t] + p2[1][t];
    __syncthreads();

    float h = (t < 128) ? h_l[t] : 0.f;
    float hn = 0.f;
#pragma unroll 1
    for (int it = 0; it < 3; it++) {
        // --- D: gh partials: 384 j x 2 k-chunks ---
        if (t < 768) {
            int kc = t / 384, j = t % 384;
            float s = 0.f;
#pragma unroll 1
            for (int kb = 0; kb < 64; kb += 16) {
                float w[16];
#pragma unroll
                for (int i = 0; i < 16; i++)
                    w[i] = WhhT[(size_t)(kc * 64 + kb + i) * 384 + j];
#pragma unroll
                for (int i = 0; i < 16; i++) s += h_l[kc * 64 + kb + i] * w[i];
            }
            p2[kc][j] = s;
        }
        __syncthreads();
        if (t < 384) gh_l[t] = b_hh[t] + p2[0][t] + p2[1][t];
        __syncthreads();
        // --- E: gates + LN ---
        if (t < 128) {
            float r = 1.f / (1.f + expf(-(gx_l[t] + gh_l[t])));
            float z = 1.f / (1.f + expf(-(gx_l[128 + t] + gh_l[128 + t])));
            float nn = tanhf(gx_l[256 + t] + r * gh_l[256 + t]);
            hn = (1.f - z) * nn + z * h;
            float s = hn, sq = hn * hn;
#pragma unroll
            for (int m = 1; m < 64; m <<= 1) { s += __shfl_xor(s, m, 64); sq += __shfl_xor(sq, m, 64); }
            if ((t & 63) == 0) { red[(t >> 6) * 2] = s; red[(t >> 6) * 2 + 1] = sq; }
        }
        __syncthreads();
        if (t < 128) {
            float s = red[0] + red[2], sq = red[1] + red[3];
            float mean = s * (1.f / 128.f), var = sq * (1.f / 128.f) - mean * mean;
            float rstd = rsqrtf(var + LN_EPS);
            m_l[t] = (hn - mean) * rstd * gm[t] + bm[t];
        }
        __syncthreads();
        // --- F: mlp1 partials: 256 j x 4 k-chunks (k=32 each) ---
        {
            int kc = t >> 8, j = t & 255;
            float s = 0.f;
#pragma unroll 1
            for (int kb = 0; kb < 32; kb += 16) {
                float w[16];
#pragma unroll
                for (int i = 0; i < 16; i++)
                    w[i] = W1[(size_t)(kc * 32 + kb + i) * 256 + j];
#pragma unroll
                for (int i = 0; i < 16; i++) s += m_l[kc * 32 + kb + i] * w[i];
            }
            p4[kc][j] = s;
        }
        __syncthreads();
        if (t < 256) {
            float a = b1v[t] + ((p4[0][t] + p4[1][t]) + (p4[2][t] + p4[3][t]));
            hid_l[t] = a / (1.f + expf(-a));   // silu
        }
        __syncthreads();
        // --- G: mlp2 partials: 128 j x 8 k-chunks (k=32 each) ---
        {
            int kc = t >> 7, j = t & 127;
            float s = 0.f;
#pragma unroll 1
            for (int kb = 0; kb < 32; kb += 16) {
                float w[16];
#pragma unroll
                for (int i = 0; i < 16; i++)
                    w[i] = W2[(size_t)(kc * 32 + kb + i) * 128 + j];
#pragma unroll
                for (int i = 0; i < 16; i++) s += hid_l[kc * 32 + kb + i] * w[i];
            }
            p8[kc][j] = s;
        }
        __syncthreads();
        if (t < 128) {
            float s = 0.f;
#pragma unroll
            for (int kc = 0; kc < 8; kc++) s += p8[kc][t];
            h = hn + b2v[t] + s;
            h_l[t] = h;
        }
        __syncthreads();
    }

    // merge: all 8 slots identical; off-diag sim = cos(h,h)
    if (t < 128) {
        float s2 = h * h;
#pragma unroll
        for (int m = 1; m < 64; m <<= 1) s2 += __shfl_xor(s2, m, 64);
        if ((t & 63) == 0) red[t >> 6] = s2;
    }
    __syncthreads();
    if (t < 128) {
        float ss = red[0] + red[1];
        float nrm = fmaxf(sqrtf(ss), 1e-12f);
        float simv = ss / (nrm * nrm);
        int allmerge = (simv > THRESH) ? 1 : 0;
#pragma unroll
        for (int sl = 0; sl < 8; sl++) {
            out_raw[((size_t)(b * 8 + sl)) * 128 + t] = h;
            float mv = (sl == 0) ? h : (allmerge ? 0.f : h);
            out_merged[((size_t)(b * 8 + sl)) * 128 + t] = mv;
        }
        if (t < 8) out_mm[b * 8 + t] = allmerge ? 0.f : (float)t;
    }
}

extern "C" void kernel_launch(void* const* d_in, const int* in_sizes, int n_in,
                              void* d_out, int out_size, void* d_ws, size_t ws_size,
                              hipStream_t stream) {
    const float* feat    = (const float*)d_in[0];
    const float* ln_in_g = (const float*)d_in[1];
    const float* ln_in_b = (const float*)d_in[2];
    const float* Wv      = (const float*)d_in[4];
    const float* W_ih    = (const float*)d_in[8];
    const float* W_hh    = (const float*)d_in[9];
    const float* b_ih    = (const float*)d_in[10];
    const float* b_hh    = (const float*)d_in[11];
    const float* ln_m_g  = (const float*)d_in[12];
    const float* ln_m_b  = (const float*)d_in[13];
    const float* W1      = (const float*)d_in[14];
    const float* b1      = (const float*)d_in[15];
    const float* W2      = (const float*)d_in[16];
    const float* b2      = (const float*)d_in[17];
    const float* slot_mu = (const float*)d_in[18];

    float* out        = (float*)d_out;
    float* out_merged = out;                       // 32768
    float* out_attn   = out + 32768;               // 1048576
    float* out_mm     = out + 32768 + 1048576;     // 256
    float* out_raw    = out_mm + 256;              // 32768

    float* G_part = (float*)d_ws;                  // [32][32][384] = 1,572,864 B
    float* WihT   = G_part + 32 * NCH * 384;       // [128][384] = 196,608 B
    float* WhhT   = WihT + 49152;                  // [128][384] = 196,608 B

    prep_kernel<<<192, 256, 0, stream>>>(W_ih, W_hh, WihT, WhhT);
    colsum_kernel<<<dim3(NCH, BATCH), 256, 0, stream>>>(feat, G_part, out_attn);
    slots_kernel<<<32, 1024, 0, stream>>>(G_part, ln_in_g, ln_in_b, Wv, slot_mu,
                                          WihT, WhhT, b_ih, b_hh, ln_m_g, ln_m_b,
                                          W1, b1, W2, b2,
                                          out_merged, out_mm, out_raw);
}